// Round 3
// baseline (304.421 us; speedup 1.0000x reference)
//
#include <hip/hip_runtime.h>

#define BATCH  8
#define NSMALL 12288
#define NFULL  24576
#define KSTEP  4096
#define JCHUNK 512   // j-tile staged in LDS
#define KCHUNK 256   // k per block (= block size)

// Step k (processed order) = original column c = KSTEP-1-k:
//   f_k = order[b][0][c], t_k = order[b][1][c];  semantics: vf[t_k] = vf[f_k]
// Provenance: root(k) = f_j at start of chain k -> J(k) -> ... where
//   J(k) = max{ j < k : t_j == f_k }. Final row n = root of its last writer.
//
// Workspace encodings need NO initialization (safe under 0xAA poison OR zeros):
//   p[b][k]    = J(k)+1      (>=1, atomicMax)  ; <=0  => no predecessor
//   gmap[b][n] = (k+1)<<15 | root (>=2^15, atomicMax); <2^15 => identity row
//   inv[b][n]  = imgpos+1    (>=1, plain store); <=0  => not in mask (zero row)

// p[b][k] via chunked O(K^2) max-match; atomicMax-combined across j-chunks
__global__ __launch_bounds__(256) void k_scan(const int* __restrict__ order,
                                              int* __restrict__ p) {
    const int b  = blockIdx.x;
    const int k0 = blockIdx.y * KCHUNK;
    const int j0 = blockIdx.z * JCHUNK;
    if (j0 >= k0 + KCHUNK) return;                        // whole chunk has j >= k

    __shared__ alignas(16) int tl[JCHUNK];
    const int* ob = order + b * 2 * KSTEP;
    for (int i = threadIdx.x; i < JCHUNK; i += 256)
        tl[i] = ob[2 * KSTEP - 1 - (j0 + i)];             // t_j for j in chunk
    __syncthreads();

    const int k  = k0 + threadIdx.x;
    const int fk = ob[KSTEP - 1 - k];
    int best = -1;

    if (j0 + JCHUNK <= k0) {                              // all j < k: no bound check
        const int4* tl4 = (const int4*)tl;
#pragma unroll 4
        for (int q = 0; q < JCHUNK / 4; ++q) {
            const int4 tv = tl4[q];
            if (tv.x == fk) best = 4 * q;
            if (tv.y == fk) best = 4 * q + 1;
            if (tv.z == fk) best = 4 * q + 2;
            if (tv.w == fk) best = 4 * q + 3;
        }
    } else {                                              // diagonal: per-lane bound
        int jmax = k - j0;
        if (jmax > JCHUNK) jmax = JCHUNK;
        for (int jj = 0; jj < jmax; ++jj)
            if (tl[jj] == fk) best = jj;
    }
    if (best >= 0) atomicMax(&p[b * KSTEP + k], j0 + best + 1);
}

// Chase chain to root row; scatter packed last-writer root into gmap.
// Also builds inv[b][row] = image position + 1 (independent work, grid-stride).
__global__ __launch_bounds__(256) void k_chase(const int* __restrict__ order,
                                               const int* __restrict__ mask_idx,
                                               const int* __restrict__ p,
                                               int* __restrict__ gmap,
                                               int* __restrict__ inv) {
    const int tid = blockIdx.x * 256 + threadIdx.x;       // B*KSTEP threads

    for (int i = tid; i < BATCH * NSMALL; i += BATCH * KSTEP) {
        const int bb = i / NSMALL, pos = i % NSMALL;
        inv[bb * NFULL + mask_idx[i]] = pos + 1;
    }

    const int b = tid / KSTEP, k = tid % KSTEP;
    const int* ob = order + b * 2 * KSTEP;
    const int* pb = p + b * KSTEP;
    int j = k, pj;
    while ((pj = pb[j]) > 0) j = pj - 1;                  // J strictly decreasing
    const int root = ob[KSTEP - 1 - j];
    const int t    = ob[2 * KSTEP - 1 - k];
    atomicMax(&gmap[b * NFULL + t], ((k + 1) << 15) | root);
}

// One wave per 256-float row; root -> image pos via inv; zero if absent.
__global__ __launch_bounds__(256) void k_copy(const float4* __restrict__ img,
                                              const int* __restrict__ gmap,
                                              const int* __restrict__ inv,
                                              float4* __restrict__ out) {
    const int r    = blockIdx.x * 4 + (threadIdx.x >> 6);
    const int lane = threadIdx.x & 63;
    const int b    = r / NFULL;
    const int g    = gmap[r];
    const int root = (g >= (1 << 15)) ? (g & 0x7fff) : (r - b * NFULL);
    const int iv   = inv[b * NFULL + root];
    float4* o = out + (size_t)r * 64 + lane;
    if (iv <= 0) *o = make_float4(0.f, 0.f, 0.f, 0.f);
    else         *o = img[((size_t)b * NSMALL + (iv - 1)) * 64 + lane];
}

extern "C" void kernel_launch(void* const* d_in, const int* in_sizes, int n_in,
                              void* d_out, int out_size, void* d_ws, size_t ws_size,
                              hipStream_t stream) {
    const float* images = (const float*)d_in[0];
    const int* mask_idx = (const int*)d_in[1];
    const int* order    = (const int*)d_in[2];
    float* out          = (float*)d_out;

    int* ws   = (int*)d_ws;
    int* p    = ws;                          // B*KSTEP
    int* gmap = p + BATCH * KSTEP;           // B*NFULL
    int* inv  = gmap + BATCH * NFULL;        // B*NFULL

    k_scan <<<dim3(BATCH, KSTEP / KCHUNK, KSTEP / JCHUNK), 256, 0, stream>>>(order, p);
    k_chase<<<BATCH * KSTEP / 256, 256, 0, stream>>>(order, mask_idx, p, gmap, inv);
    k_copy <<<BATCH * NFULL / 4, 256, 0, stream>>>((const float4*)images, gmap,
                                                   inv, (float4*)out);
}